// Round 12
// baseline (467.732 us; speedup 1.0000x reference)
//
#include <hip/hip_runtime.h>
#include <hip/hip_bf16.h>
#include <math.h>

#define BN_EPS 1e-5f

typedef __attribute__((ext_vector_type(8))) short short8v;   // 8 x bf16
typedef __attribute__((ext_vector_type(4))) float f32x4;

__device__ inline float bf_lo(unsigned int p) { return __uint_as_float(p << 16); }
__device__ inline float bf_hi(unsigned int p) { return __uint_as_float(p & 0xffff0000u); }
__device__ inline unsigned int packbf(float a, float b) {
    unsigned short lo = __builtin_bit_cast(unsigned short, __float2bfloat16(a));
    unsigned short hi = __builtin_bit_cast(unsigned short, __float2bfloat16(b));
    return (unsigned int)lo | ((unsigned int)hi << 16);
}

// ---------------- degree precompute ----------------

__global__ __launch_bounds__(256) void deg_kernel(const int* __restrict__ row, const int* __restrict__ col,
                                                  float* __restrict__ deg_src, float* __restrict__ deg_dst, int E) {
    int e = blockIdx.x * 256 + threadIdx.x;
    if (e < E) {
        atomicAdd(&deg_src[row[e]], 1.0f);
        atomicAdd(&deg_dst[col[e]], 1.0f);
    }
}

// W^T in bf16: Wt[l][c][k] = W[l][k][c]
__global__ __launch_bounds__(256) void wt_kernel(const float* __restrict__ Ws, __hip_bfloat16* __restrict__ Wt) {
    int idx = blockIdx.x * 256 + threadIdx.x;
    if (idx < 3 * 16384) {
        int l = idx >> 14, rem = idx & 16383, c = rem >> 7, k = rem & 127;
        Wt[idx] = __float2bfloat16(Ws[(l << 14) + (k << 7) + c]);
    }
}

// ---------------- CSR build: hierarchical exclusive scan + fill ----------------

__global__ __launch_bounds__(256) void scan_pass1(const float* __restrict__ deg, int* __restrict__ blockSums,
                                                  int N, int PT) {
    __shared__ int lds[256];
    const int tid = threadIdx.x;
    const int start = (blockIdx.x * 256 + tid) * PT;
    int s = 0;
    for (int i = 0; i < PT; ++i) {
        int idx = start + i;
        if (idx < N) s += (int)deg[idx];
    }
    lds[tid] = s;
    __syncthreads();
    for (int d = 128; d > 0; d >>= 1) {
        if (tid < d) lds[tid] += lds[tid + d];
        __syncthreads();
    }
    if (tid == 0) blockSums[blockIdx.x] = lds[0];
}

__global__ __launch_bounds__(256) void scan_pass2(const int* __restrict__ blockSums, int* __restrict__ blockOffs) {
    __shared__ int lds[256];
    const int tid = threadIdx.x;
    int v = blockSums[tid];
    lds[tid] = v;
    __syncthreads();
    for (int d = 1; d < 256; d <<= 1) {
        int t = (tid >= d) ? lds[tid - d] : 0;
        __syncthreads();
        lds[tid] += t;
        __syncthreads();
    }
    blockOffs[tid] = lds[tid] - v;
}

__global__ __launch_bounds__(256) void scan_pass3(const float* __restrict__ deg, const int* __restrict__ blockOffs,
                                                  int* __restrict__ off, int* __restrict__ cur,
                                                  int N, int PT, int E) {
    __shared__ int lds[256];
    const int tid = threadIdx.x;
    const int start = (blockIdx.x * 256 + tid) * PT;
    int s = 0;
    for (int i = 0; i < PT; ++i) {
        int idx = start + i;
        if (idx < N) s += (int)deg[idx];
    }
    lds[tid] = s;
    __syncthreads();
    for (int d = 1; d < 256; d <<= 1) {
        int t = (tid >= d) ? lds[tid - d] : 0;
        __syncthreads();
        lds[tid] += t;
        __syncthreads();
    }
    int prefix = blockOffs[blockIdx.x] + lds[tid] - s;
    for (int i = 0; i < PT; ++i) {
        int idx = start + i;
        if (idx < N) {
            off[idx] = prefix;
            cur[idx] = prefix;
            prefix += (int)deg[idx];
        }
    }
    if (blockIdx.x == 0 && tid == 0) off[N] = E;
}

// meta[p] = (src, bitcast(weight)); dinv computed on the fly from raw degrees
__global__ __launch_bounds__(256) void fill_kernel(const int* __restrict__ row, const int* __restrict__ col,
                                                   const float* __restrict__ deg_dst, int* __restrict__ cur,
                                                   int2* __restrict__ meta, int E) {
    int e = blockIdx.x * 256 + threadIdx.x;
    if (e < E) {
        int r = row[e], t = col[e];
        int p = atomicAdd(&cur[t], 1);
        float dr = deg_dst[r], dt = deg_dst[t];
        float ir = (dr > 0.0f) ? rsqrtf(dr) : 0.0f;
        float it = (dt > 0.0f) ? rsqrtf(dt) : 0.0f;
        meta[p] = make_int2(r, __float_as_int(ir * it));
    }
}

// ---------------- fused initx + GEMM (layer 0): H = [emb | log(deg+1)] @ W0 ----------------
// Reads f32 emb directly; builds bf16 A-frags in-register (same rounding as initx+gemm).
// Exact grid: 1 job per wave. block 0 zeroes the BN sums accumulator.

__global__ __launch_bounds__(256) void gemm0_fused(const float* __restrict__ emb, const float* __restrict__ deg_src,
                                                   const __hip_bfloat16* __restrict__ Wt,
                                                   __hip_bfloat16* __restrict__ H, float* __restrict__ sums,
                                                   int totalJobs, int N) {
    if (blockIdx.x == 0) sums[threadIdx.x] = 0.0f;

    const int lane = threadIdx.x & 63;
    const int wv = threadIdx.x >> 6;
    const int job = blockIdx.x * 4 + wv;
    if (job >= totalJobs) return;
    const int r = lane & 15;
    const int q = lane >> 4;
    const int ch = job & 1;
    const int s = job >> 1;
    const int arow = s * 16 + r;

    short8v bfrag[4][4];
#pragma unroll
    for (int ct = 0; ct < 4; ++ct)
#pragma unroll
        for (int kk = 0; kk < 4; ++kk)
            bfrag[ct][kk] = *(const short8v*)(Wt + ((ch * 64 + ct * 16 + r) << 7) + kk * 32 + q * 8);

    short8v a[4] = {{}, {}, {}, {}};
    if (arow < N) {
        const float* ep = emb + (size_t)arow * 127;
#pragma unroll
        for (int kk = 0; kk < 4; ++kk) {
            const int c0 = q * 8 + kk * 32;
            float x[8];
            if (c0 < 120) {                 // generic: 8 contiguous f32 (align-4 vector loads)
                f32x4 v0, v1;
                __builtin_memcpy(&v0, ep + c0, 16);
                __builtin_memcpy(&v1, ep + c0 + 4, 16);
#pragma unroll
                for (int j = 0; j < 4; ++j) { x[j] = v0[j]; x[4 + j] = v1[j]; }
            } else {                        // c0 == 120: channels 120..126 + log-degree
                f32x4 v0;
                __builtin_memcpy(&v0, ep + 120, 16);
                float2 v1;
                __builtin_memcpy(&v1, ep + 124, 8);
#pragma unroll
                for (int j = 0; j < 4; ++j) x[j] = v0[j];
                x[4] = v1.x; x[5] = v1.y;
                x[6] = ep[126];
                x[7] = logf(deg_src[arow] + 1.0f);
            }
            unsigned int* au = (unsigned int*)&a[kk];
#pragma unroll
            for (int j = 0; j < 4; ++j) au[j] = packbf(x[2 * j], x[2 * j + 1]);
        }
    }
    f32x4 acc[4];
#pragma unroll
    for (int ct = 0; ct < 4; ++ct) {
        f32x4 c = {0.f, 0.f, 0.f, 0.f};
        c = __builtin_amdgcn_mfma_f32_16x16x32_bf16(a[0], bfrag[ct][0], c, 0, 0, 0);
        c = __builtin_amdgcn_mfma_f32_16x16x32_bf16(a[1], bfrag[ct][1], c, 0, 0, 0);
        c = __builtin_amdgcn_mfma_f32_16x16x32_bf16(a[2], bfrag[ct][2], c, 0, 0, 0);
        c = __builtin_amdgcn_mfma_f32_16x16x32_bf16(a[3], bfrag[ct][3], c, 0, 0, 0);
        acc[ct] = c;
    }
#pragma unroll
    for (int g = 0; g < 4; ++g) {
        int grow = s * 16 + q * 4 + g;
        if (grow < N) {
            __hip_bfloat16* hp = H + ((size_t)grow << 7) + ch * 64 + r;
#pragma unroll
            for (int ct = 0; ct < 4; ++ct)
                hp[ct * 16] = __float2bfloat16(acc[ct][g]);
        }
    }
}

// ---------------- fused BN-apply + GEMM (layers 1,2) ----------------
// BN scale/shift once per block into LDS; exact grid (1 job/wave); ch==0 waves write x.

template <int MODE>
__global__ __launch_bounds__(256) void bn_gemm(const unsigned int* __restrict__ aggb, const float* __restrict__ sums,
                                               const float* __restrict__ gamma, const float* __restrict__ beta,
                                               const unsigned int* __restrict__ xprevb, unsigned int* __restrict__ xoutb,
                                               const __hip_bfloat16* __restrict__ Wt, __hip_bfloat16* __restrict__ H,
                                               float* __restrict__ sumsNext, int totalJobs, int N, float invN) {
    __shared__ float ssc[128], ssh[128];
    const int tid = threadIdx.x;
    if (blockIdx.x == 0) sumsNext[tid] = 0.0f;
    if (tid < 128) {
        float m = sums[tid] * invN;
        float v = sums[128 + tid] * invN - m * m;
        float inv = rsqrtf(fmaxf(v, 0.0f) + BN_EPS);
        float sc = gamma[tid] * inv;
        ssc[tid] = sc;
        ssh[tid] = beta[tid] - m * sc;
    }
    __syncthreads();

    const int lane = tid & 63;
    const int wv = tid >> 6;
    const int job = blockIdx.x * 4 + wv;
    if (job >= totalJobs) return;
    const int r = lane & 15;
    const int q = lane >> 4;
    const int ch = job & 1;
    const int s = job >> 1;
    const int arow = s * 16 + r;

    short8v bfrag[4][4];
#pragma unroll
    for (int ct = 0; ct < 4; ++ct)
#pragma unroll
        for (int kk = 0; kk < 4; ++kk)
            bfrag[ct][kk] = *(const short8v*)(Wt + ((ch * 64 + ct * 16 + r) << 7) + kk * 32 + q * 8);

    short8v a[4] = {{}, {}, {}, {}};
    if (arow < N) {
        const size_t rbase = ((size_t)arow << 6) + q * 4;
#pragma unroll
        for (int kk = 0; kk < 4; ++kk) {
            const int c0 = q * 8 + kk * 32;
            float sc[8], sh[8];
            *(float4*)&sc[0] = *(const float4*)&ssc[c0];
            *(float4*)&sc[4] = *(const float4*)&ssc[c0 + 4];
            *(float4*)&sh[0] = *(const float4*)&ssh[c0];
            *(float4*)&sh[4] = *(const float4*)&ssh[c0 + 4];
            uint4 av = *(const uint4*)(aggb + rbase + kk * 16);
            const unsigned int* au = (const unsigned int*)&av;
            float x[8];
#pragma unroll
            for (int j = 0; j < 4; ++j) {
                x[2 * j]     = fmaxf(fmaf(bf_lo(au[j]), sc[2 * j],     sh[2 * j]),     0.f);
                x[2 * j + 1] = fmaxf(fmaf(bf_hi(au[j]), sc[2 * j + 1], sh[2 * j + 1]), 0.f);
            }
            if (MODE == 1) {
                uint4 xv = *(const uint4*)(xprevb + rbase + kk * 16);
                const unsigned int* xu = (const unsigned int*)&xv;
#pragma unroll
                for (int j = 0; j < 4; ++j) {
                    x[2 * j]     = fmaf(0.5f, bf_lo(xu[j]), x[2 * j]);
                    x[2 * j + 1] = fmaf(0.5f, bf_hi(xu[j]), x[2 * j + 1]);
                }
            }
            uint4 pk;
            unsigned int* pku = (unsigned int*)&pk;
#pragma unroll
            for (int j = 0; j < 4; ++j) pku[j] = packbf(x[2 * j], x[2 * j + 1]);
            if (ch == 0) *(uint4*)(xoutb + rbase + kk * 16) = pk;
#pragma unroll
            for (int j = 0; j < 4; ++j) ((unsigned int*)&a[kk])[j] = pku[j];
        }
    }
    f32x4 acc[4];
#pragma unroll
    for (int ct = 0; ct < 4; ++ct) {
        f32x4 c = {0.f, 0.f, 0.f, 0.f};
        c = __builtin_amdgcn_mfma_f32_16x16x32_bf16(a[0], bfrag[ct][0], c, 0, 0, 0);
        c = __builtin_amdgcn_mfma_f32_16x16x32_bf16(a[1], bfrag[ct][1], c, 0, 0, 0);
        c = __builtin_amdgcn_mfma_f32_16x16x32_bf16(a[2], bfrag[ct][2], c, 0, 0, 0);
        c = __builtin_amdgcn_mfma_f32_16x16x32_bf16(a[3], bfrag[ct][3], c, 0, 0, 0);
        acc[ct] = c;
    }
#pragma unroll
    for (int g = 0; g < 4; ++g) {
        int grow = s * 16 + q * 4 + g;
        if (grow < N) {
            __hip_bfloat16* hp = H + ((size_t)grow << 7) + ch * 64 + r;
#pragma unroll
            for (int ct = 0; ct < 4; ++ct)
                hp[ct * 16] = __float2bfloat16(acc[ct][g]);
        }
    }
}

// ---------------- dual-node CSR-vector gather + bias + fused BN partial stats ----------------
// R6-exact (best measured: 76-79 µs across four rounds). Do not restructure.

__global__ __launch_bounds__(256) void gather_kernel(const __hip_bfloat16* __restrict__ h,
                                                     const int* __restrict__ off, const int2* __restrict__ meta,
                                                     const float* __restrict__ bias,
                                                     unsigned int* __restrict__ aggb, float* __restrict__ sums, int N) {
    __shared__ float sm[2][4][128];
    const int tid = threadIdx.x;
    const int lane = tid & 63;
    const int w = tid >> 6;       // wave 0..3
    const int g = lane >> 4;      // edge slot 0..3
    const int s = lane & 15;      // channel octet: channels 8s..8s+7

    float b8[8];
    *(float4*)&b8[0] = *(const float4*)&bias[s * 8];
    *(float4*)&b8[4] = *(const float4*)&bias[s * 8 + 4];

    float psum[8], psq[8];
#pragma unroll
    for (int j = 0; j < 8; ++j) { psum[j] = 0.f; psq[j] = 0.f; }

    for (int base = (blockIdx.x * 4 + w) * 2; base < N; base += gridDim.x * 8) {
        const int nA = __builtin_amdgcn_readfirstlane(base);
        const int hasB = (nA + 1 < N);
        const int sA = off[nA];
        const int eA = off[nA + 1];
        const int eB = hasB ? off[nA + 2] : eA;

        float accA[8], accB[8];
#pragma unroll
        for (int j = 0; j < 8; ++j) { accA[j] = 0.f; accB[j] = 0.f; }

        int iA = sA, iB = eA;   // B's segment starts where A's ends
        while (iA < eA || iB < eB) {
            int i0A = iA + g, i1A = iA + 4 + g;
            int i0B = iB + g, i1B = iB + 4 + g;
            int idx0A = (i0A < eA) ? i0A : 0;
            int idx1A = (i1A < eA) ? i1A : 0;
            int idx0B = (i0B < eB) ? i0B : 0;
            int idx1B = (i1B < eB) ? i1B : 0;
            int2 m0A = meta[idx0A], m1A = meta[idx1A];
            int2 m0B = meta[idx0B], m1B = meta[idx1B];
            float w0A = (i0A < eA) ? __int_as_float(m0A.y) : 0.f;
            float w1A = (i1A < eA) ? __int_as_float(m1A.y) : 0.f;
            float w0B = (i0B < eB) ? __int_as_float(m0B.y) : 0.f;
            float w1B = (i1B < eB) ? __int_as_float(m1B.y) : 0.f;
            short8v h0A = *(const short8v*)(h + ((size_t)m0A.x << 7) + s * 8);
            short8v h1A = *(const short8v*)(h + ((size_t)m1A.x << 7) + s * 8);
            short8v h0B = *(const short8v*)(h + ((size_t)m0B.x << 7) + s * 8);
            short8v h1B = *(const short8v*)(h + ((size_t)m1B.x << 7) + s * 8);
#pragma unroll
            for (int j = 0; j < 4; ++j) {
                unsigned int u;
                u = ((const unsigned int*)&h0A)[j];
                accA[2 * j]     = fmaf(w0A, bf_lo(u), accA[2 * j]);
                accA[2 * j + 1] = fmaf(w0A, bf_hi(u), accA[2 * j + 1]);
                u = ((const unsigned int*)&h1A)[j];
                accA[2 * j]     = fmaf(w1A, bf_lo(u), accA[2 * j]);
                accA[2 * j + 1] = fmaf(w1A, bf_hi(u), accA[2 * j + 1]);
                u = ((const unsigned int*)&h0B)[j];
                accB[2 * j]     = fmaf(w0B, bf_lo(u), accB[2 * j]);
                accB[2 * j + 1] = fmaf(w0B, bf_hi(u), accB[2 * j + 1]);
                u = ((const unsigned int*)&h1B)[j];
                accB[2 * j]     = fmaf(w1B, bf_lo(u), accB[2 * j]);
                accB[2 * j + 1] = fmaf(w1B, bf_hi(u), accB[2 * j + 1]);
            }
            iA += 8; iB += 8;
        }
        // fold the 4 edge slots; add bias (all lanes end with full sums)
#pragma unroll
        for (int j = 0; j < 8; ++j) {
            accA[j] += __shfl_xor(accA[j], 16);
            accA[j] += __shfl_xor(accA[j], 32);
            accA[j] += b8[j];
            accB[j] += __shfl_xor(accB[j], 16);
            accB[j] += __shfl_xor(accB[j], 32);
            accB[j] += b8[j];
        }
        if (g == 0) {
            unsigned int pk[4];
#pragma unroll
            for (int j = 0; j < 4; ++j) pk[j] = packbf(accA[2 * j], accA[2 * j + 1]);
            *(uint4*)(aggb + ((size_t)nA << 6) + s * 4) = *(uint4*)pk;
#pragma unroll
            for (int j = 0; j < 8; ++j) {
                psum[j] += accA[j];
                psq[j] = fmaf(accA[j], accA[j], psq[j]);
            }
            if (hasB) {
#pragma unroll
                for (int j = 0; j < 8; ++j) {
                    psum[j] += accB[j];
                    psq[j] = fmaf(accB[j], accB[j], psq[j]);
                }
            }
        } else if (g == 1 && hasB) {
            unsigned int pk[4];
#pragma unroll
            for (int j = 0; j < 4; ++j) pk[j] = packbf(accB[2 * j], accB[2 * j + 1]);
            *(uint4*)(aggb + ((size_t)(nA + 1) << 6) + s * 4) = *(uint4*)pk;
        }
    }
    if (g == 0) {
#pragma unroll
        for (int j = 0; j < 8; ++j) {
            sm[0][w][s * 8 + j] = psum[j];
            sm[1][w][s * 8 + j] = psq[j];
        }
    }
    __syncthreads();
    if (tid < 128) {
        atomicAdd(&sums[tid], sm[0][0][tid] + sm[0][1][tid] + sm[0][2][tid] + sm[0][3][tid]);
    } else {
        int c = tid - 128;
        atomicAdd(&sums[128 + c], sm[1][0][c] + sm[1][1][c] + sm[1][2][c] + sm[1][3][c]);
    }
}

// ---------------- final batchnorm apply (f32 out + residual) ----------------

__global__ __launch_bounds__(256) void bn_out(const unsigned int* __restrict__ aggb, const float* __restrict__ sums,
                                              const float* __restrict__ gamma, const float* __restrict__ beta,
                                              const uint4* __restrict__ xprev, float* __restrict__ xout,
                                              int NO, float invN) {
    int idx = blockIdx.x * 256 + threadIdx.x;
    if (idx >= NO) return;
    const int c0 = (idx & 15) * 8;

    float su[8], sq[8], gm[8], bt[8];
    *(float4*)&su[0] = *(const float4*)&sums[c0];
    *(float4*)&su[4] = *(const float4*)&sums[c0 + 4];
    *(float4*)&sq[0] = *(const float4*)&sums[128 + c0];
    *(float4*)&sq[4] = *(const float4*)&sums[128 + c0 + 4];
    *(float4*)&gm[0] = *(const float4*)&gamma[c0];
    *(float4*)&gm[4] = *(const float4*)&gamma[c0 + 4];
    *(float4*)&bt[0] = *(const float4*)&beta[c0];
    *(float4*)&bt[4] = *(const float4*)&beta[c0 + 4];

    float sc[8], sh[8];
#pragma unroll
    for (int j = 0; j < 8; ++j) {
        float m = su[j] * invN;
        float v = sq[j] * invN - m * m;
        float inv = rsqrtf(fmaxf(v, 0.0f) + BN_EPS);
        sc[j] = gm[j] * inv;
        sh[j] = bt[j] - m * sc[j];
    }

    uint4 av = *(const uint4*)(aggb + (size_t)idx * 4);
    const unsigned int* au = (const unsigned int*)&av;
    float r[8];
#pragma unroll
    for (int j = 0; j < 4; ++j) {
        r[2 * j]     = fmaxf(fmaf(bf_lo(au[j]), sc[2 * j],     sh[2 * j]),     0.f);
        r[2 * j + 1] = fmaxf(fmaf(bf_hi(au[j]), sc[2 * j + 1], sh[2 * j + 1]), 0.f);
    }
    uint4 xv = xprev[idx];
    const unsigned int* xu = (const unsigned int*)&xv;
#pragma unroll
    for (int j = 0; j < 4; ++j) {
        r[2 * j]     = fmaf(0.5f, bf_lo(xu[j]), r[2 * j]);
        r[2 * j + 1] = fmaf(0.5f, bf_hi(xu[j]), r[2 * j + 1]);
    }
    float* op = xout + (size_t)idx * 8;
    *(float4*)op       = make_float4(r[0], r[1], r[2], r[3]);
    *(float4*)(op + 4) = make_float4(r[4], r[5], r[6], r[7]);
}

// ---------------- launch ----------------

extern "C" void kernel_launch(void* const* d_in, const int* in_sizes, int n_in,
                              void* d_out, int out_size, void* d_ws, size_t ws_size,
                              hipStream_t stream) {
    const float* emb    = (const float*)d_in[0];
    const float* Ws     = (const float*)d_in[1];
    const float* bs     = (const float*)d_in[2];
    const float* gammas = (const float*)d_in[3];
    const float* betas  = (const float*)d_in[4];
    const int*   ei     = (const int*)d_in[5];

    const int N = in_sizes[0] / 127;
    const int E = in_sizes[5] / 2;
    const int* row = ei;
    const int* col = ei + E;
    float* out = (float*)d_out;

    const size_t NH = (size_t)N * 128;
    __hip_bfloat16* XA = (__hip_bfloat16*)d_ws;
    __hip_bfloat16* XB = XA + NH;
    unsigned int*  AGG = (unsigned int*)(XB + NH);      // NH/2 uints (bf16 pairs)
    int2*         meta = (int2*)(AGG + NH / 2);         // E
    __hip_bfloat16* Wt = (__hip_bfloat16*)(meta + E);   // 3*16384
    float* deg_src = (float*)(Wt + 3 * 16384);          // N
    float* deg_dst = deg_src + N;                       // N
    float* sumsA   = deg_dst + N;                       // 256
    float* sumsB   = sumsA + 256;                       // 256
    int*   cur     = (int*)(sumsB + 256);               // N
    int*   blockSums = cur + N;                         // 256
    int*   blockOffs = blockSums + 256;                 // 256
    int*   off     = blockOffs + 256;                   // N+1

    __hip_bfloat16* H2 = (__hip_bfloat16*)out;          // h2 scratch inside d_out (overwritten by bn_out)

    const int NO = (int)(NH / 8);          // octets
    const int PT = (N + 65535) / 65536;
    const int nStripes = (N + 15) / 16;
    const int totalJobs = nStripes * 2;
    const int gemmGrid = (totalJobs + 3) / 4;
    const float invN = 1.0f / (float)N;

    hipMemsetAsync(deg_src, 0, sizeof(float) * 2 * (size_t)N, stream);
    wt_kernel<<<(3 * 16384 + 255) / 256, 256, 0, stream>>>(Ws, Wt);
    deg_kernel<<<(E + 255) / 256, 256, 0, stream>>>(row, col, deg_src, deg_dst, E);
    scan_pass1<<<256, 256, 0, stream>>>(deg_dst, blockSums, N, PT);
    scan_pass2<<<1, 256, 0, stream>>>(blockSums, blockOffs);
    scan_pass3<<<256, 256, 0, stream>>>(deg_dst, blockOffs, off, cur, N, PT, E);
    fill_kernel<<<(E + 255) / 256, 256, 0, stream>>>(row, col, deg_dst, cur, meta, E);

    // L0: h0 = [emb | logdeg] @ W0 -> XB ; gather -> AGG, sumsA
    gemm0_fused<<<gemmGrid, 256, 0, stream>>>(emb, deg_src, Wt, XB, sumsA, totalJobs, N);
    gather_kernel<<<2048, 256, 0, stream>>>(XB, off, meta, bs, AGG, sumsA, N);

    // L1 (no residual): x1 = relu(bn0(AGG)) -> XA ; h1 = x1@W1 -> XB ; zero sumsB
    bn_gemm<0><<<gemmGrid, 256, 0, stream>>>(AGG, sumsA, gammas, betas, nullptr,
                                             (unsigned int*)XA, Wt + 16384, XB, sumsB, totalJobs, N, invN);
    gather_kernel<<<2048, 256, 0, stream>>>(XB, off, meta, bs + 128, AGG, sumsB, N);

    // L2 (residual 0.5*x1): x2 -> XB ; h2 = x2@W2 -> H2(out) ; zero sumsA
    bn_gemm<1><<<gemmGrid, 256, 0, stream>>>(AGG, sumsB, gammas + 128, betas + 128, (const unsigned int*)XA,
                                             (unsigned int*)XB, Wt + 2 * 16384, H2, sumsA, totalJobs, N, invN);
    gather_kernel<<<2048, 256, 0, stream>>>(H2, off, meta, bs + 256, AGG, sumsA, N);

    // out = relu(bn2(AGG)) + 0.5*x2  (f32)
    bn_out<<<(NO + 255) / 256, 256, 0, stream>>>(AGG, sumsA, gammas + 256, betas + 256,
                                                 (const uint4*)XB, out, NO, invN);
}

// Round 13
// 421.129 us; speedup vs baseline: 1.1107x; 1.1107x over previous
//
#include <hip/hip_runtime.h>
#include <hip/hip_bf16.h>
#include <math.h>

#define BN_EPS 1e-5f

typedef __attribute__((ext_vector_type(8))) short short8v;   // 8 x bf16
typedef __attribute__((ext_vector_type(4))) float f32x4;

__device__ inline float bf_lo(unsigned int p) { return __uint_as_float(p << 16); }
__device__ inline float bf_hi(unsigned int p) { return __uint_as_float(p & 0xffff0000u); }
__device__ inline unsigned int packbf(float a, float b) {
    unsigned short lo = __builtin_bit_cast(unsigned short, __float2bfloat16(a));
    unsigned short hi = __builtin_bit_cast(unsigned short, __float2bfloat16(b));
    return (unsigned int)lo | ((unsigned int)hi << 16);
}

// ---------------- degree precompute ----------------

__global__ __launch_bounds__(256) void deg_kernel(const int* __restrict__ row, const int* __restrict__ col,
                                                  float* __restrict__ deg_src, float* __restrict__ deg_dst, int E) {
    int e = blockIdx.x * 256 + threadIdx.x;
    if (e < E) {
        atomicAdd(&deg_src[row[e]], 1.0f);
        atomicAdd(&deg_dst[col[e]], 1.0f);
    }
}

// W^T in bf16: Wt[l][c][k] = W[l][k][c]
__global__ __launch_bounds__(256) void wt_kernel(const float* __restrict__ Ws, __hip_bfloat16* __restrict__ Wt) {
    int idx = blockIdx.x * 256 + threadIdx.x;
    if (idx < 3 * 16384) {
        int l = idx >> 14, rem = idx & 16383, c = rem >> 7, k = rem & 127;
        Wt[idx] = __float2bfloat16(Ws[(l << 14) + (k << 7) + c]);
    }
}

// ---------------- CSR build: hierarchical exclusive scan + fill ----------------

__global__ __launch_bounds__(256) void scan_pass1(const float* __restrict__ deg, int* __restrict__ blockSums,
                                                  int N, int PT) {
    __shared__ int lds[256];
    const int tid = threadIdx.x;
    const int start = (blockIdx.x * 256 + tid) * PT;
    int s = 0;
    for (int i = 0; i < PT; ++i) {
        int idx = start + i;
        if (idx < N) s += (int)deg[idx];
    }
    lds[tid] = s;
    __syncthreads();
    for (int d = 128; d > 0; d >>= 1) {
        if (tid < d) lds[tid] += lds[tid + d];
        __syncthreads();
    }
    if (tid == 0) blockSums[blockIdx.x] = lds[0];
}

__global__ __launch_bounds__(256) void scan_pass2(const int* __restrict__ blockSums, int* __restrict__ blockOffs) {
    __shared__ int lds[256];
    const int tid = threadIdx.x;
    int v = blockSums[tid];
    lds[tid] = v;
    __syncthreads();
    for (int d = 1; d < 256; d <<= 1) {
        int t = (tid >= d) ? lds[tid - d] : 0;
        __syncthreads();
        lds[tid] += t;
        __syncthreads();
    }
    blockOffs[tid] = lds[tid] - v;
}

__global__ __launch_bounds__(256) void scan_pass3(const float* __restrict__ deg, const int* __restrict__ blockOffs,
                                                  int* __restrict__ off, int* __restrict__ cur,
                                                  int N, int PT, int E) {
    __shared__ int lds[256];
    const int tid = threadIdx.x;
    const int start = (blockIdx.x * 256 + tid) * PT;
    int s = 0;
    for (int i = 0; i < PT; ++i) {
        int idx = start + i;
        if (idx < N) s += (int)deg[idx];
    }
    lds[tid] = s;
    __syncthreads();
    for (int d = 1; d < 256; d <<= 1) {
        int t = (tid >= d) ? lds[tid - d] : 0;
        __syncthreads();
        lds[tid] += t;
        __syncthreads();
    }
    int prefix = blockOffs[blockIdx.x] + lds[tid] - s;
    for (int i = 0; i < PT; ++i) {
        int idx = start + i;
        if (idx < N) {
            off[idx] = prefix;
            cur[idx] = prefix;
            prefix += (int)deg[idx];
        }
    }
    if (blockIdx.x == 0 && tid == 0) off[N] = E;
}

// meta[p] = (src, bitcast(weight)); dinv computed on the fly from raw degrees
__global__ __launch_bounds__(256) void fill_kernel(const int* __restrict__ row, const int* __restrict__ col,
                                                   const float* __restrict__ deg_dst, int* __restrict__ cur,
                                                   int2* __restrict__ meta, int E) {
    int e = blockIdx.x * 256 + threadIdx.x;
    if (e < E) {
        int r = row[e], t = col[e];
        int p = atomicAdd(&cur[t], 1);
        float dr = deg_dst[r], dt = deg_dst[t];
        float ir = (dr > 0.0f) ? rsqrtf(dr) : 0.0f;
        float it = (dt > 0.0f) ? rsqrtf(dt) : 0.0f;
        meta[p] = make_int2(r, __float_as_int(ir * it));
    }
}

// ---------------- fused initx + GEMM (layer 0): H = [emb | log(deg+1)] @ W0 ----------------
// PERSISTENT loop (1024 blocks, bfrag amortized over ~3 jobs/wave — R12's exact grid regressed).
// Reads f32 emb directly; builds bf16 A-frags in-register (same rounding as initx+gemm).

__global__ __launch_bounds__(256) void gemm0_fused(const float* __restrict__ emb, const float* __restrict__ deg_src,
                                                   const __hip_bfloat16* __restrict__ Wt,
                                                   __hip_bfloat16* __restrict__ H, float* __restrict__ sums,
                                                   int nStripes, int N) {
    if (blockIdx.x == 0) sums[threadIdx.x] = 0.0f;

    const int lane = threadIdx.x & 63;
    const int wv = threadIdx.x >> 6;
    const int r = lane & 15;
    const int q = lane >> 4;
    const int ch = (blockIdx.x * 4 + wv) & 1;   // stride gridDim*4 is even -> constant per wave

    short8v bfrag[4][4];
#pragma unroll
    for (int ct = 0; ct < 4; ++ct)
#pragma unroll
        for (int kk = 0; kk < 4; ++kk)
            bfrag[ct][kk] = *(const short8v*)(Wt + ((ch * 64 + ct * 16 + r) << 7) + kk * 32 + q * 8);

    const int totalJobs = nStripes * 2;
    for (int job = blockIdx.x * 4 + wv; job < totalJobs; job += gridDim.x * 4) {
        const int s = job >> 1;
        const int arow = s * 16 + r;
        short8v a[4] = {{}, {}, {}, {}};
        if (arow < N) {
            const float* ep = emb + (size_t)arow * 127;
#pragma unroll
            for (int kk = 0; kk < 4; ++kk) {
                const int c0 = q * 8 + kk * 32;
                float x[8];
                if (c0 < 120) {                 // generic: 8 contiguous f32 (align-4 vector loads)
                    f32x4 v0, v1;
                    __builtin_memcpy(&v0, ep + c0, 16);
                    __builtin_memcpy(&v1, ep + c0 + 4, 16);
#pragma unroll
                    for (int j = 0; j < 4; ++j) { x[j] = v0[j]; x[4 + j] = v1[j]; }
                } else {                        // c0 == 120: channels 120..126 + log-degree
                    f32x4 v0;
                    __builtin_memcpy(&v0, ep + 120, 16);
                    float2 v1;
                    __builtin_memcpy(&v1, ep + 124, 8);
#pragma unroll
                    for (int j = 0; j < 4; ++j) x[j] = v0[j];
                    x[4] = v1.x; x[5] = v1.y;
                    x[6] = ep[126];
                    x[7] = logf(deg_src[arow] + 1.0f);
                }
                unsigned int* au = (unsigned int*)&a[kk];
#pragma unroll
                for (int j = 0; j < 4; ++j) au[j] = packbf(x[2 * j], x[2 * j + 1]);
            }
        }
        f32x4 acc[4];
#pragma unroll
        for (int ct = 0; ct < 4; ++ct) {
            f32x4 c = {0.f, 0.f, 0.f, 0.f};
            c = __builtin_amdgcn_mfma_f32_16x16x32_bf16(a[0], bfrag[ct][0], c, 0, 0, 0);
            c = __builtin_amdgcn_mfma_f32_16x16x32_bf16(a[1], bfrag[ct][1], c, 0, 0, 0);
            c = __builtin_amdgcn_mfma_f32_16x16x32_bf16(a[2], bfrag[ct][2], c, 0, 0, 0);
            c = __builtin_amdgcn_mfma_f32_16x16x32_bf16(a[3], bfrag[ct][3], c, 0, 0, 0);
            acc[ct] = c;
        }
#pragma unroll
        for (int g = 0; g < 4; ++g) {
            int grow = s * 16 + q * 4 + g;
            if (grow < N) {
                __hip_bfloat16* hp = H + ((size_t)grow << 7) + ch * 64 + r;
#pragma unroll
                for (int ct = 0; ct < 4; ++ct)
                    hp[ct * 16] = __float2bfloat16(acc[ct][g]);
            }
        }
    }
}

// ---------------- fused BN-apply + GEMM (layers 1,2) ----------------
// R11-exact: BN scale/shift once per block into LDS; persistent loop; ch==0 waves write x.

template <int MODE>
__global__ __launch_bounds__(256) void bn_gemm(const unsigned int* __restrict__ aggb, const float* __restrict__ sums,
                                               const float* __restrict__ gamma, const float* __restrict__ beta,
                                               const unsigned int* __restrict__ xprevb, unsigned int* __restrict__ xoutb,
                                               const __hip_bfloat16* __restrict__ Wt, __hip_bfloat16* __restrict__ H,
                                               float* __restrict__ sumsNext, int nStripes, int N, float invN) {
    __shared__ float ssc[128], ssh[128];
    const int tid = threadIdx.x;
    if (blockIdx.x == 0) sumsNext[tid] = 0.0f;
    if (tid < 128) {
        float m = sums[tid] * invN;
        float v = sums[128 + tid] * invN - m * m;
        float inv = rsqrtf(fmaxf(v, 0.0f) + BN_EPS);
        float sc = gamma[tid] * inv;
        ssc[tid] = sc;
        ssh[tid] = beta[tid] - m * sc;
    }
    __syncthreads();

    const int lane = tid & 63;
    const int wv = tid >> 6;
    const int r = lane & 15;
    const int q = lane >> 4;
    const int ch = (blockIdx.x * 4 + wv) & 1;

    short8v bfrag[4][4];
#pragma unroll
    for (int ct = 0; ct < 4; ++ct)
#pragma unroll
        for (int kk = 0; kk < 4; ++kk)
            bfrag[ct][kk] = *(const short8v*)(Wt + ((ch * 64 + ct * 16 + r) << 7) + kk * 32 + q * 8);

    const int totalJobs = nStripes * 2;
    for (int job = blockIdx.x * 4 + wv; job < totalJobs; job += gridDim.x * 4) {
        const int s = job >> 1;
        const int arow = s * 16 + r;
        short8v a[4] = {{}, {}, {}, {}};
        if (arow < N) {
            const size_t rbase = ((size_t)arow << 6) + q * 4;
#pragma unroll
            for (int kk = 0; kk < 4; ++kk) {
                const int c0 = q * 8 + kk * 32;
                float sc[8], sh[8];
                *(float4*)&sc[0] = *(const float4*)&ssc[c0];
                *(float4*)&sc[4] = *(const float4*)&ssc[c0 + 4];
                *(float4*)&sh[0] = *(const float4*)&ssh[c0];
                *(float4*)&sh[4] = *(const float4*)&ssh[c0 + 4];
                uint4 av = *(const uint4*)(aggb + rbase + kk * 16);
                const unsigned int* au = (const unsigned int*)&av;
                float x[8];
#pragma unroll
                for (int j = 0; j < 4; ++j) {
                    x[2 * j]     = fmaxf(fmaf(bf_lo(au[j]), sc[2 * j],     sh[2 * j]),     0.f);
                    x[2 * j + 1] = fmaxf(fmaf(bf_hi(au[j]), sc[2 * j + 1], sh[2 * j + 1]), 0.f);
                }
                if (MODE == 1) {
                    uint4 xv = *(const uint4*)(xprevb + rbase + kk * 16);
                    const unsigned int* xu = (const unsigned int*)&xv;
#pragma unroll
                    for (int j = 0; j < 4; ++j) {
                        x[2 * j]     = fmaf(0.5f, bf_lo(xu[j]), x[2 * j]);
                        x[2 * j + 1] = fmaf(0.5f, bf_hi(xu[j]), x[2 * j + 1]);
                    }
                }
                uint4 pk;
                unsigned int* pku = (unsigned int*)&pk;
#pragma unroll
                for (int j = 0; j < 4; ++j) pku[j] = packbf(x[2 * j], x[2 * j + 1]);
                if (ch == 0) *(uint4*)(xoutb + rbase + kk * 16) = pk;
#pragma unroll
                for (int j = 0; j < 4; ++j) ((unsigned int*)&a[kk])[j] = pku[j];
            }
        }
        f32x4 acc[4];
#pragma unroll
        for (int ct = 0; ct < 4; ++ct) {
            f32x4 c = {0.f, 0.f, 0.f, 0.f};
            c = __builtin_amdgcn_mfma_f32_16x16x32_bf16(a[0], bfrag[ct][0], c, 0, 0, 0);
            c = __builtin_amdgcn_mfma_f32_16x16x32_bf16(a[1], bfrag[ct][1], c, 0, 0, 0);
            c = __builtin_amdgcn_mfma_f32_16x16x32_bf16(a[2], bfrag[ct][2], c, 0, 0, 0);
            c = __builtin_amdgcn_mfma_f32_16x16x32_bf16(a[3], bfrag[ct][3], c, 0, 0, 0);
            acc[ct] = c;
        }
#pragma unroll
        for (int g = 0; g < 4; ++g) {
            int grow = s * 16 + q * 4 + g;
            if (grow < N) {
                __hip_bfloat16* hp = H + ((size_t)grow << 7) + ch * 64 + r;
#pragma unroll
                for (int ct = 0; ct < 4; ++ct)
                    hp[ct * 16] = __float2bfloat16(acc[ct][g]);
            }
        }
    }
}

// ---------------- dual-node CSR-vector gather + bias + fused BN partial stats ----------------
// R6-exact (best measured: 76-79 µs across five rounds). Do not restructure.

__global__ __launch_bounds__(256) void gather_kernel(const __hip_bfloat16* __restrict__ h,
                                                     const int* __restrict__ off, const int2* __restrict__ meta,
                                                     const float* __restrict__ bias,
                                                     unsigned int* __restrict__ aggb, float* __restrict__ sums, int N) {
    __shared__ float sm[2][4][128];
    const int tid = threadIdx.x;
    const int lane = tid & 63;
    const int w = tid >> 6;       // wave 0..3
    const int g = lane >> 4;      // edge slot 0..3
    const int s = lane & 15;      // channel octet: channels 8s..8s+7

    float b8[8];
    *(float4*)&b8[0] = *(const float4*)&bias[s * 8];
    *(float4*)&b8[4] = *(const float4*)&bias[s * 8 + 4];

    float psum[8], psq[8];
#pragma unroll
    for (int j = 0; j < 8; ++j) { psum[j] = 0.f; psq[j] = 0.f; }

    for (int base = (blockIdx.x * 4 + w) * 2; base < N; base += gridDim.x * 8) {
        const int nA = __builtin_amdgcn_readfirstlane(base);
        const int hasB = (nA + 1 < N);
        const int sA = off[nA];
        const int eA = off[nA + 1];
        const int eB = hasB ? off[nA + 2] : eA;

        float accA[8], accB[8];
#pragma unroll
        for (int j = 0; j < 8; ++j) { accA[j] = 0.f; accB[j] = 0.f; }

        int iA = sA, iB = eA;   // B's segment starts where A's ends
        while (iA < eA || iB < eB) {
            int i0A = iA + g, i1A = iA + 4 + g;
            int i0B = iB + g, i1B = iB + 4 + g;
            int idx0A = (i0A < eA) ? i0A : 0;
            int idx1A = (i1A < eA) ? i1A : 0;
            int idx0B = (i0B < eB) ? i0B : 0;
            int idx1B = (i1B < eB) ? i1B : 0;
            int2 m0A = meta[idx0A], m1A = meta[idx1A];
            int2 m0B = meta[idx0B], m1B = meta[idx1B];
            float w0A = (i0A < eA) ? __int_as_float(m0A.y) : 0.f;
            float w1A = (i1A < eA) ? __int_as_float(m1A.y) : 0.f;
            float w0B = (i0B < eB) ? __int_as_float(m0B.y) : 0.f;
            float w1B = (i1B < eB) ? __int_as_float(m1B.y) : 0.f;
            short8v h0A = *(const short8v*)(h + ((size_t)m0A.x << 7) + s * 8);
            short8v h1A = *(const short8v*)(h + ((size_t)m1A.x << 7) + s * 8);
            short8v h0B = *(const short8v*)(h + ((size_t)m0B.x << 7) + s * 8);
            short8v h1B = *(const short8v*)(h + ((size_t)m1B.x << 7) + s * 8);
#pragma unroll
            for (int j = 0; j < 4; ++j) {
                unsigned int u;
                u = ((const unsigned int*)&h0A)[j];
                accA[2 * j]     = fmaf(w0A, bf_lo(u), accA[2 * j]);
                accA[2 * j + 1] = fmaf(w0A, bf_hi(u), accA[2 * j + 1]);
                u = ((const unsigned int*)&h1A)[j];
                accA[2 * j]     = fmaf(w1A, bf_lo(u), accA[2 * j]);
                accA[2 * j + 1] = fmaf(w1A, bf_hi(u), accA[2 * j + 1]);
                u = ((const unsigned int*)&h0B)[j];
                accB[2 * j]     = fmaf(w0B, bf_lo(u), accB[2 * j]);
                accB[2 * j + 1] = fmaf(w0B, bf_hi(u), accB[2 * j + 1]);
                u = ((const unsigned int*)&h1B)[j];
                accB[2 * j]     = fmaf(w1B, bf_lo(u), accB[2 * j]);
                accB[2 * j + 1] = fmaf(w1B, bf_hi(u), accB[2 * j + 1]);
            }
            iA += 8; iB += 8;
        }
        // fold the 4 edge slots; add bias (all lanes end with full sums)
#pragma unroll
        for (int j = 0; j < 8; ++j) {
            accA[j] += __shfl_xor(accA[j], 16);
            accA[j] += __shfl_xor(accA[j], 32);
            accA[j] += b8[j];
            accB[j] += __shfl_xor(accB[j], 16);
            accB[j] += __shfl_xor(accB[j], 32);
            accB[j] += b8[j];
        }
        if (g == 0) {
            unsigned int pk[4];
#pragma unroll
            for (int j = 0; j < 4; ++j) pk[j] = packbf(accA[2 * j], accA[2 * j + 1]);
            *(uint4*)(aggb + ((size_t)nA << 6) + s * 4) = *(uint4*)pk;
#pragma unroll
            for (int j = 0; j < 8; ++j) {
                psum[j] += accA[j];
                psq[j] = fmaf(accA[j], accA[j], psq[j]);
            }
            if (hasB) {
#pragma unroll
                for (int j = 0; j < 8; ++j) {
                    psum[j] += accB[j];
                    psq[j] = fmaf(accB[j], accB[j], psq[j]);
                }
            }
        } else if (g == 1 && hasB) {
            unsigned int pk[4];
#pragma unroll
            for (int j = 0; j < 4; ++j) pk[j] = packbf(accB[2 * j], accB[2 * j + 1]);
            *(uint4*)(aggb + ((size_t)(nA + 1) << 6) + s * 4) = *(uint4*)pk;
        }
    }
    if (g == 0) {
#pragma unroll
        for (int j = 0; j < 8; ++j) {
            sm[0][w][s * 8 + j] = psum[j];
            sm[1][w][s * 8 + j] = psq[j];
        }
    }
    __syncthreads();
    if (tid < 128) {
        atomicAdd(&sums[tid], sm[0][0][tid] + sm[0][1][tid] + sm[0][2][tid] + sm[0][3][tid]);
    } else {
        int c = tid - 128;
        atomicAdd(&sums[128 + c], sm[1][0][c] + sm[1][1][c] + sm[1][2][c] + sm[1][3][c]);
    }
}

// ---------------- final batchnorm apply (f32 out + residual) ----------------

__global__ __launch_bounds__(256) void bn_out(const unsigned int* __restrict__ aggb, const float* __restrict__ sums,
                                              const float* __restrict__ gamma, const float* __restrict__ beta,
                                              const uint4* __restrict__ xprev, float* __restrict__ xout,
                                              int NO, float invN) {
    int idx = blockIdx.x * 256 + threadIdx.x;
    if (idx >= NO) return;
    const int c0 = (idx & 15) * 8;

    float su[8], sq[8], gm[8], bt[8];
    *(float4*)&su[0] = *(const float4*)&sums[c0];
    *(float4*)&su[4] = *(const float4*)&sums[c0 + 4];
    *(float4*)&sq[0] = *(const float4*)&sums[128 + c0];
    *(float4*)&sq[4] = *(const float4*)&sums[128 + c0 + 4];
    *(float4*)&gm[0] = *(const float4*)&gamma[c0];
    *(float4*)&gm[4] = *(const float4*)&gamma[c0 + 4];
    *(float4*)&bt[0] = *(const float4*)&beta[c0];
    *(float4*)&bt[4] = *(const float4*)&beta[c0 + 4];

    float sc[8], sh[8];
#pragma unroll
    for (int j = 0; j < 8; ++j) {
        float m = su[j] * invN;
        float v = sq[j] * invN - m * m;
        float inv = rsqrtf(fmaxf(v, 0.0f) + BN_EPS);
        sc[j] = gm[j] * inv;
        sh[j] = bt[j] - m * sc[j];
    }

    uint4 av = *(const uint4*)(aggb + (size_t)idx * 4);
    const unsigned int* au = (const unsigned int*)&av;
    float r[8];
#pragma unroll
    for (int j = 0; j < 4; ++j) {
        r[2 * j]     = fmaxf(fmaf(bf_lo(au[j]), sc[2 * j],     sh[2 * j]),     0.f);
        r[2 * j + 1] = fmaxf(fmaf(bf_hi(au[j]), sc[2 * j + 1], sh[2 * j + 1]), 0.f);
    }
    uint4 xv = xprev[idx];
    const unsigned int* xu = (const unsigned int*)&xv;
#pragma unroll
    for (int j = 0; j < 4; ++j) {
        r[2 * j]     = fmaf(0.5f, bf_lo(xu[j]), r[2 * j]);
        r[2 * j + 1] = fmaf(0.5f, bf_hi(xu[j]), r[2 * j + 1]);
    }
    float* op = xout + (size_t)idx * 8;
    *(float4*)op       = make_float4(r[0], r[1], r[2], r[3]);
    *(float4*)(op + 4) = make_float4(r[4], r[5], r[6], r[7]);
}

// ---------------- launch ----------------

extern "C" void kernel_launch(void* const* d_in, const int* in_sizes, int n_in,
                              void* d_out, int out_size, void* d_ws, size_t ws_size,
                              hipStream_t stream) {
    const float* emb    = (const float*)d_in[0];
    const float* Ws     = (const float*)d_in[1];
    const float* bs     = (const float*)d_in[2];
    const float* gammas = (const float*)d_in[3];
    const float* betas  = (const float*)d_in[4];
    const int*   ei     = (const int*)d_in[5];

    const int N = in_sizes[0] / 127;
    const int E = in_sizes[5] / 2;
    const int* row = ei;
    const int* col = ei + E;
    float* out = (float*)d_out;

    const size_t NH = (size_t)N * 128;
    __hip_bfloat16* XA = (__hip_bfloat16*)d_ws;
    __hip_bfloat16* XB = XA + NH;
    unsigned int*  AGG = (unsigned int*)(XB + NH);      // NH/2 uints (bf16 pairs)
    int2*         meta = (int2*)(AGG + NH / 2);         // E
    __hip_bfloat16* Wt = (__hip_bfloat16*)(meta + E);   // 3*16384
    float* deg_src = (float*)(Wt + 3 * 16384);          // N
    float* deg_dst = deg_src + N;                       // N
    float* sumsA   = deg_dst + N;                       // 256
    float* sumsB   = sumsA + 256;                       // 256
    int*   cur     = (int*)(sumsB + 256);               // N
    int*   blockSums = cur + N;                         // 256
    int*   blockOffs = blockSums + 256;                 // 256
    int*   off     = blockOffs + 256;                   // N+1

    __hip_bfloat16* H2 = (__hip_bfloat16*)out;          // h2 scratch inside d_out (overwritten by bn_out)

    const int NO = (int)(NH / 8);          // octets
    const int PT = (N + 65535) / 65536;
    const int nStripes = (N + 15) / 16;
    const float invN = 1.0f / (float)N;

    hipMemsetAsync(deg_src, 0, sizeof(float) * 2 * (size_t)N, stream);
    wt_kernel<<<(3 * 16384 + 255) / 256, 256, 0, stream>>>(Ws, Wt);
    deg_kernel<<<(E + 255) / 256, 256, 0, stream>>>(row, col, deg_src, deg_dst, E);
    scan_pass1<<<256, 256, 0, stream>>>(deg_dst, blockSums, N, PT);
    scan_pass2<<<1, 256, 0, stream>>>(blockSums, blockOffs);
    scan_pass3<<<256, 256, 0, stream>>>(deg_dst, blockOffs, off, cur, N, PT, E);
    fill_kernel<<<(E + 255) / 256, 256, 0, stream>>>(row, col, deg_dst, cur, meta, E);

    // L0: h0 = [emb | logdeg] @ W0 -> XB ; gather -> AGG, sumsA
    gemm0_fused<<<1024, 256, 0, stream>>>(emb, deg_src, Wt, XB, sumsA, nStripes, N);
    gather_kernel<<<2048, 256, 0, stream>>>(XB, off, meta, bs, AGG, sumsA, N);

    // L1 (no residual): x1 = relu(bn0(AGG)) -> XA ; h1 = x1@W1 -> XB ; zero sumsB
    bn_gemm<0><<<1024, 256, 0, stream>>>(AGG, sumsA, gammas, betas, nullptr,
                                         (unsigned int*)XA, Wt + 16384, XB, sumsB, nStripes, N, invN);
    gather_kernel<<<2048, 256, 0, stream>>>(XB, off, meta, bs + 128, AGG, sumsB, N);

    // L2 (residual 0.5*x1): x2 -> XB ; h2 = x2@W2 -> H2(out) ; zero sumsA
    bn_gemm<1><<<1024, 256, 0, stream>>>(AGG, sumsB, gammas + 128, betas + 128, (const unsigned int*)XA,
                                         (unsigned int*)XB, Wt + 2 * 16384, H2, sumsA, nStripes, N, invN);
    gather_kernel<<<2048, 256, 0, stream>>>(H2, off, meta, bs + 256, AGG, sumsA, N);

    // out = relu(bn2(AGG)) + 0.5*x2  (f32)
    bn_out<<<(NO + 255) / 256, 256, 0, stream>>>(AGG, sumsA, gammas + 256, betas + 256,
                                                 (const uint4*)XB, out, NO, invN);
}